// Round 2
// baseline (16994.661 us; speedup 1.0000x reference)
//
#include <hip/hip_runtime.h>
#include <cstdint>
#include <cstddef>

// ---------------------------------------------------------------------------
// E2E AttDot + 2-layer LSTM decoder + CE loss, bf16 MFMA implementation.
// B=32, T=400, E=D=1024, V=5000, L=100 (101 steps). Loss = mean(CE)*100.
// R2: affine K-loops via X-ring buffers, pipelined k_att, vectorized partials.
// ---------------------------------------------------------------------------

using short8  = __attribute__((ext_vector_type(8))) short;
using floatx4 = __attribute__((ext_vector_type(4))) float;
typedef unsigned int uv4 __attribute__((ext_vector_type(4)));
typedef unsigned int uv2 __attribute__((ext_vector_type(2)));

#define DEV __device__ __forceinline__

DEV float bf2f(unsigned int h) { union { unsigned int u; float f; } v; v.u = h << 16; return v.f; }
DEV unsigned short f2bf(float f) {
    union { float f; unsigned int u; } v; v.f = f;
    return (unsigned short)((v.u + 0x7fffu + ((v.u >> 16) & 1u)) >> 16);
}
DEV float sigm(float x) { return 1.0f / (1.0f + __expf(-x)); }

// ---------------------------------------------------------------- utilities
__global__ __launch_bounds__(256) void k_zero(unsigned int* p, int n) {
    int i = blockIdx.x * 256 + threadIdx.x;
    if (i < n) p[i] = 0u;
}

__global__ __launch_bounds__(256) void k_conv4(const float* __restrict__ in,
                                               unsigned short* __restrict__ out, int n4) {
    int i = blockIdx.x * 256 + threadIdx.x;
    if (i >= n4) return;
    float4 v = ((const float4*)in)[i];
    unsigned int w0 = (unsigned int)f2bf(v.x) | ((unsigned int)f2bf(v.y) << 16);
    unsigned int w1 = (unsigned int)f2bf(v.z) | ((unsigned int)f2bf(v.w) << 16);
    ((uint2*)(void*)out)[i] = make_uint2(w0, w1);
}

__global__ __launch_bounds__(256) void k_cat2(const float* __restrict__ A, const float* __restrict__ Bsrc,
                                              unsigned short* __restrict__ dst, int N, int Ka, int Kb) {
    int idx = blockIdx.x * 256 + threadIdx.x;
    int K = Ka + Kb;
    if (idx >= N * K) return;
    int n = idx / K, k = idx - n * K;
    float v = (k < Ka) ? A[(size_t)n * Ka + k] : Bsrc[(size_t)n * Kb + (k - Ka)];
    dst[idx] = f2bf(v);
}

__global__ __launch_bounds__(256) void k_woutpad(const float* __restrict__ W, unsigned short* __restrict__ dst) {
    int idx = blockIdx.x * 256 + threadIdx.x;
    if (idx >= 5120 * 2048) return;
    int n = idx >> 11, k = idx & 2047;
    dst[idx] = (n < 5000) ? f2bf(W[(size_t)n * 2048 + k]) : (unsigned short)0;
}

__global__ __launch_bounds__(256) void k_bsum(const float* a0, const float* b0, const float* a1, const float* b1,
                                              float* s0, float* s1) {
    int i = blockIdx.x * 256 + threadIdx.x;
    if (i < 4096) s0[i] = a0[i] + b0[i];
    else if (i < 8192) s1[i - 4096] = a1[i - 4096] + b1[i - 4096];
}

// eys[l][b][d] = bf16(embed[ys_in[b][l]][d])
__global__ __launch_bounds__(256) void k_eys(const float* __restrict__ embed, const int* __restrict__ ys_pad,
                                             unsigned short* __restrict__ eys) {
    int idx = blockIdx.x * 256 + threadIdx.x;
    if (idx >= 3232 * 1024) return;
    int rb = idx >> 10, d = idx & 1023;
    int l = rb >> 5, b = rb & 31;
    int tok = (l == 0) ? 4999 : ys_pad[b * 100 + (l - 1)];
    eys[idx] = f2bf(embed[(size_t)tok * 1024 + d]);
}

// --------------------------------------------------- big 128x128 MFMA GEMM
__global__ __launch_bounds__(256) void k_gemm128(
    const unsigned short* __restrict__ A, const unsigned short* __restrict__ B,
    int K, int N, const float* __restrict__ bias,
    unsigned short* __restrict__ obf, float* __restrict__ of32, int mode) {
    __shared__ uint4 Ab[512];
    __shared__ uint4 Bb[512];
    const int tid = threadIdx.x;
    const int lane = tid & 63, wave = tid >> 6;
    const int r = lane & 15, q = lane >> 4;
    const int wm = wave >> 1, wn = wave & 1;
    const size_t am0 = (size_t)blockIdx.y * 128;
    const size_t bn0 = (size_t)blockIdx.x * 128;
    floatx4 zf = {0.f, 0.f, 0.f, 0.f};
    floatx4 acc[4][4];
#pragma unroll
    for (int i = 0; i < 4; i++)
#pragma unroll
        for (int j = 0; j < 4; j++) acc[i][j] = zf;

    for (int k0 = 0; k0 < K; k0 += 32) {
        __syncthreads();
#pragma unroll
        for (int i = 0; i < 2; ++i) {
            int idx = i * 256 + tid;
            int qq = idx & 3, rr = idx >> 2;
            int slot = (rr >> 4) * 64 + ((qq << 4) | (rr & 15));
            Ab[slot] = *(const uint4*)(const void*)(A + (am0 + rr) * K + k0 + qq * 8);
            Bb[slot] = *(const uint4*)(const void*)(B + (bn0 + rr) * K + k0 + qq * 8);
        }
        __syncthreads();
        short8 af[4], bf[4];
#pragma unroll
        for (int t = 0; t < 4; t++) af[t] = *(const short8*)(const void*)&Ab[(wm * 4 + t) * 64 + lane];
#pragma unroll
        for (int t = 0; t < 4; t++) bf[t] = *(const short8*)(const void*)&Bb[(wn * 4 + t) * 64 + lane];
#pragma unroll
        for (int tm = 0; tm < 4; tm++)
#pragma unroll
            for (int tn = 0; tn < 4; tn++)
                acc[tm][tn] = __builtin_amdgcn_mfma_f32_16x16x32_bf16(af[tm], bf[tn], acc[tm][tn], 0, 0, 0);
    }
#pragma unroll
    for (int tm = 0; tm < 4; tm++) {
#pragma unroll
        for (int tn = 0; tn < 4; tn++) {
            int col = (int)bn0 + wn * 64 + tn * 16 + r;
#pragma unroll
            for (int reg = 0; reg < 4; ++reg) {
                size_t row = am0 + wm * 64 + tm * 16 + q * 4 + reg;
                float v = acc[tm][tn][reg];
                if (mode == 0) {
                    v = tanhf(v + bias[col]);
                    obf[row * (size_t)N + col] = f2bf(v);
                } else {
                    of32[row * (size_t)N + col] = v;
                }
            }
        }
    }
}

// ------------------------------------------------------------ dq (32x1024)
// dq[b][d] = tanh( sum_k z0[b][k]*Wdec[d][k] + bdec[d] ); z0 rows have pitch `apitch`
DEV void dq_role(int dcq, const unsigned short* __restrict__ Wdec,
                 const unsigned short* __restrict__ z0, int apitch,
                 const float* __restrict__ bdec, unsigned short* __restrict__ dq) {
    const int tid = threadIdx.x, lane = tid & 63, wave = tid >> 6;
    if (wave >= 2) return;
    const int r = lane & 15, q = lane >> 4, mt = wave;
    floatx4 acc = {0.f, 0.f, 0.f, 0.f};
    const unsigned short* Brow = Wdec + (size_t)(dcq * 16 + r) * 1024 + q * 8;
    const unsigned short* Arow = z0 + (size_t)(mt * 16 + r) * apitch + q * 8;
#pragma unroll
    for (int k0 = 0; k0 < 1024; k0 += 32) {
        short8 bfr = *(const short8*)(const void*)(Brow + k0);
        short8 afr = *(const short8*)(const void*)(Arow + k0);
        acc = __builtin_amdgcn_mfma_f32_16x16x32_bf16(afr, bfr, acc, 0, 0, 0);
    }
    const int n = dcq * 16 + r;
#pragma unroll
    for (int reg = 0; reg < 4; ++reg) {
        int m = mt * 16 + q * 4 + reg;
        dq[m * 1024 + n] = f2bf(tanhf(acc[reg] + bdec[n]));
    }
}

__global__ __launch_bounds__(256) void k_dq(const unsigned short* __restrict__ Wdec,
                                            const unsigned short* __restrict__ z0, int apitch,
                                            const float* __restrict__ bdec,
                                            unsigned short* __restrict__ dq) {
    dq_role(blockIdx.x, Wdec, z0, apitch, bdec, dq);
}

// ------------------------------------------------------- attention per step
// grid 256 = 32 b x 8 chunks(50 t). Pipelined dots + LDS finish; last block
// per b merges -> att into X0R[l] + z_all, and copies ey row into X0R[l].
__global__ __launch_bounds__(256) void k_att(
    const unsigned short* __restrict__ pre, const unsigned short* __restrict__ hs,
    const unsigned short* __restrict__ dq, const int* __restrict__ hlens,
    const unsigned short* __restrict__ eyrow,   // EYS + l*32*1024
    unsigned short* __restrict__ x0,            // X0R[l&1], pitch 3072
    float* __restrict__ part, float* __restrict__ lmax_g, float* __restrict__ lsum_g,
    unsigned short* __restrict__ z_all, int* __restrict__ cnt, int step) {
    const int b = blockIdx.x >> 3, ch = blockIdx.x & 7;
    const int tid = threadIdx.x, lane = tid & 63, wave = tid >> 6;
    const int hlen = hlens[b];
    __shared__ float e4[50][4];
    __shared__ float es[50];
    __shared__ float ps[52];
    __shared__ int lastflag;

    float dqf[16];
    {
        const uint4* dp = (const uint4*)(const void*)(dq + b * 1024 + lane * 16);
        uint4 w0 = dp[0], w1 = dp[1];
        dqf[0] = bf2f(w0.x & 0xffffu); dqf[1] = bf2f(w0.x >> 16);
        dqf[2] = bf2f(w0.y & 0xffffu); dqf[3] = bf2f(w0.y >> 16);
        dqf[4] = bf2f(w0.z & 0xffffu); dqf[5] = bf2f(w0.z >> 16);
        dqf[6] = bf2f(w0.w & 0xffffu); dqf[7] = bf2f(w0.w >> 16);
        dqf[8]  = bf2f(w1.x & 0xffffu); dqf[9]  = bf2f(w1.x >> 16);
        dqf[10] = bf2f(w1.y & 0xffffu); dqf[11] = bf2f(w1.y >> 16);
        dqf[12] = bf2f(w1.z & 0xffffu); dqf[13] = bf2f(w1.z >> 16);
        dqf[14] = bf2f(w1.w & 0xffffu); dqf[15] = bf2f(w1.w >> 16);
    }
    // stage 1: partial dots, NT loads, 4-shuffle partial reduce
    const unsigned short* preb = pre + ((size_t)(b * 400 + ch * 50)) * 1024 + lane * 16;
    for (int tl = wave; tl < 50; tl += 4) {
        uv4 v0 = __builtin_nontemporal_load((const uv4*)(const void*)(preb + (size_t)tl * 1024));
        uv4 v1 = __builtin_nontemporal_load((const uv4*)(const void*)(preb + (size_t)tl * 1024 + 8));
        float s = 0.f;
        s += bf2f(v0.x & 0xffffu) * dqf[0] + bf2f(v0.x >> 16) * dqf[1];
        s += bf2f(v0.y & 0xffffu) * dqf[2] + bf2f(v0.y >> 16) * dqf[3];
        s += bf2f(v0.z & 0xffffu) * dqf[4] + bf2f(v0.z >> 16) * dqf[5];
        s += bf2f(v0.w & 0xffffu) * dqf[6] + bf2f(v0.w >> 16) * dqf[7];
        s += bf2f(v1.x & 0xffffu) * dqf[8]  + bf2f(v1.x >> 16) * dqf[9];
        s += bf2f(v1.y & 0xffffu) * dqf[10] + bf2f(v1.y >> 16) * dqf[11];
        s += bf2f(v1.z & 0xffffu) * dqf[12] + bf2f(v1.z >> 16) * dqf[13];
        s += bf2f(v1.w & 0xffffu) * dqf[14] + bf2f(v1.w >> 16) * dqf[15];
        s += __shfl_xor(s, 1, 64);
        s += __shfl_xor(s, 2, 64);
        s += __shfl_xor(s, 4, 64);
        s += __shfl_xor(s, 8, 64);
        if ((lane & 15) == 0) e4[tl][lane >> 4] = s;
    }
    __syncthreads();
    if (tid < 50) {
        float4 v = *(const float4*)(const void*)e4[tid];
        float e = v.x + v.y + v.z + v.w;
        int t = ch * 50 + tid;
        es[tid] = (t < hlen) ? 2.0f * e : -1e30f;
    }
    __syncthreads();
    float lmax = -1e30f;
#pragma unroll
    for (int i = 0; i < 50; ++i) lmax = fmaxf(lmax, es[i]);
    if (tid < 50) ps[tid] = (es[tid] > -5e29f) ? __expf(es[tid] - lmax) : 0.f;
    __syncthreads();
    if (tid == 0) {
        float ssum = 0.f;
        for (int i = 0; i < 50; ++i) ssum += ps[i];
        lmax_g[b * 8 + ch] = lmax;
        lsum_g[b * 8 + ch] = ssum;
    }
    // stage 4: partial att_c, branch-free
    const int c = tid * 4;
    float a0 = 0.f, a1 = 0.f, a2 = 0.f, a3 = 0.f;
    const unsigned short* hsb = hs + ((size_t)(b * 400 + ch * 50)) * 1024 + c;
    for (int tl = 0; tl < 50; ++tl) {
        float p = ps[tl];
        uv2 h = __builtin_nontemporal_load((const uv2*)(const void*)(hsb + (size_t)tl * 1024));
        a0 += p * bf2f(h.x & 0xffffu); a1 += p * bf2f(h.x >> 16);
        a2 += p * bf2f(h.y & 0xffffu); a3 += p * bf2f(h.y >> 16);
    }
    {
        float4 st = make_float4(a0, a1, a2, a3);
        *(float4*)(void*)(part + ((size_t)(b * 8 + ch)) * 1024 + c) = st;
    }
    __threadfence();
    __syncthreads();
    if (tid == 0) lastflag = (atomicAdd(cnt + b, 1) == 8 * step + 7);
    __syncthreads();
    if (!lastflag) return;
    __threadfence();
    // merge 8 chunks
    float lm[8], ls[8];
#pragma unroll
    for (int i = 0; i < 8; ++i) { lm[i] = lmax_g[b * 8 + i]; ls[i] = lsum_g[b * 8 + i]; }
    float gm = -1e30f;
#pragma unroll
    for (int i = 0; i < 8; ++i) gm = fmaxf(gm, lm[i]);
    float Zs = 0.f;
#pragma unroll
    for (int i = 0; i < 8; ++i) Zs += ls[i] * __expf(lm[i] - gm);
    const float inv = 1.0f / Zs;
    float o0 = 0.f, o1 = 0.f, o2 = 0.f, o3 = 0.f;
#pragma unroll
    for (int i = 0; i < 8; ++i) {
        float coef = __expf(lm[i] - gm) * inv;
        float4 q4 = *(const float4*)(const void*)(part + ((size_t)(b * 8 + i)) * 1024 + c);
        o0 += coef * q4.x; o1 += coef * q4.y; o2 += coef * q4.z; o3 += coef * q4.w;
    }
    uint2 attp;
    attp.x = (unsigned int)f2bf(o0) | ((unsigned int)f2bf(o1) << 16);
    attp.y = (unsigned int)f2bf(o2) | ((unsigned int)f2bf(o3) << 16);
    *(uint2*)(void*)(x0 + (size_t)b * 3072 + 1024 + c) = attp;
    *(uint2*)(void*)(z_all + ((size_t)(step * 32 + b)) * 2048 + 1024 + c) = attp;
    // ey copy into X0R[l]
    uint2 ey = *(const uint2*)(const void*)(eyrow + b * 1024 + c);
    *(uint2*)(void*)(x0 + (size_t)b * 3072 + c) = ey;
}

// ------------------------------------------------------------ LSTM cell 0
// gates = X0R[l] @ Wcat0^T (K=3072), split-K x4, affine K-loop.
__global__ __launch_bounds__(256) void k_cell0(
    const unsigned short* __restrict__ W, const unsigned short* __restrict__ X,
    unsigned short* __restrict__ z0a,  // X1R[l&1] base, pitch 2048
    unsigned short* __restrict__ z0b,  // X0R[(l+1)&1] + 2048, pitch 3072
    float* __restrict__ c0, float* __restrict__ gp, const float* __restrict__ bsum,
    int* __restrict__ cnt, int step) {
    const int tid = threadIdx.x, lane = tid & 63, g = tid >> 6;
    const int r = lane & 15, q = lane >> 4;
    const int dc = blockIdx.x >> 2, kc = blockIdx.x & 3;
    const unsigned short* Br = W + ((size_t)(g * 1024 + dc * 16 + r)) * 3072 + kc * 768 + q * 8;
    const unsigned short* A0 = X + (size_t)r * 3072 + kc * 768 + q * 8;
    const unsigned short* A1 = A0 + 16 * 3072;
    floatx4 acc0 = {0.f, 0.f, 0.f, 0.f}, acc1 = acc0;
#pragma unroll
    for (int kk = 0; kk < 768; kk += 32) {
        short8 bfr = *(const short8*)(const void*)(Br + kk);
        short8 a0  = *(const short8*)(const void*)(A0 + kk);
        short8 a1  = *(const short8*)(const void*)(A1 + kk);
        acc0 = __builtin_amdgcn_mfma_f32_16x16x32_bf16(a0, bfr, acc0, 0, 0, 0);
        acc1 = __builtin_amdgcn_mfma_f32_16x16x32_bf16(a1, bfr, acc1, 0, 0, 0);
    }
    const int n = g * 1024 + dc * 16 + r;
    float* gb = gp + ((size_t)kc * 4096 + n) * 32;
    *(floatx4*)(void*)(gb + q * 4) = acc0;
    *(floatx4*)(void*)(gb + 16 + q * 4) = acc1;
    __threadfence();
    __syncthreads();
    __shared__ int lastflag;
    if (tid == 0) lastflag = (atomicAdd(cnt + dc, 1) == 4 * step + 3);
    __syncthreads();
    if (!lastflag) return;
    __threadfence();
    for (int idx = tid; idx < 512; idx += 256) {
        const int bb = idx & 31, dl = idx >> 5;
        const int d = dc * 16 + dl;
        float gg[4];
#pragma unroll
        for (int gate = 0; gate < 4; ++gate) {
            float s = bsum[gate * 1024 + d];
#pragma unroll
            for (int kcc = 0; kcc < 4; ++kcc)
                s += gp[((size_t)kcc * 4096 + gate * 1024 + d) * 32 + bb];
            gg[gate] = s;
        }
        const float cn = sigm(gg[1]) * c0[d * 32 + bb] + sigm(gg[0]) * tanhf(gg[2]);
        c0[d * 32 + bb] = cn;
        const unsigned short hb = f2bf(sigm(gg[3]) * tanhf(cn));
        z0a[bb * 2048 + d] = hb;
        z0b[bb * 3072 + d] = hb;
    }
}

// --------------------------------------------- LSTM cell 1 + next-step dq
__global__ __launch_bounds__(256) void k_cell1dq(
    const unsigned short* __restrict__ W, const unsigned short* __restrict__ X,  // X1R[l&1], pitch 2048
    unsigned short* __restrict__ z1out,  // X1R[(l+1)&1] + 1024, pitch 2048
    float* __restrict__ c1, float* __restrict__ gp, const float* __restrict__ bsum,
    int* __restrict__ cnt, const unsigned short* __restrict__ Wdec,
    const float* __restrict__ bdec, unsigned short* __restrict__ dq,
    unsigned short* __restrict__ z_all, int step) {
    const int bi = blockIdx.x;
    if (bi >= 256) { dq_role(bi - 256, Wdec, X, 2048, bdec, dq); return; }
    const int tid = threadIdx.x, lane = tid & 63, g = tid >> 6;
    const int r = lane & 15, q = lane >> 4;
    const int dc = bi >> 2, kc = bi & 3;
    const unsigned short* Br = W + ((size_t)(g * 1024 + dc * 16 + r)) * 2048 + kc * 512 + q * 8;
    const unsigned short* A0 = X + (size_t)r * 2048 + kc * 512 + q * 8;
    const unsigned short* A1 = A0 + 16 * 2048;
    floatx4 acc0 = {0.f, 0.f, 0.f, 0.f}, acc1 = acc0;
#pragma unroll
    for (int kk = 0; kk < 512; kk += 32) {
        short8 bfr = *(const short8*)(const void*)(Br + kk);
        short8 a0  = *(const short8*)(const void*)(A0 + kk);
        short8 a1  = *(const short8*)(const void*)(A1 + kk);
        acc0 = __builtin_amdgcn_mfma_f32_16x16x32_bf16(a0, bfr, acc0, 0, 0, 0);
        acc1 = __builtin_amdgcn_mfma_f32_16x16x32_bf16(a1, bfr, acc1, 0, 0, 0);
    }
    const int n = g * 1024 + dc * 16 + r;
    float* gb = gp + ((size_t)kc * 4096 + n) * 32;
    *(floatx4*)(void*)(gb + q * 4) = acc0;
    *(floatx4*)(void*)(gb + 16 + q * 4) = acc1;
    __threadfence();
    __syncthreads();
    __shared__ int lastflag;
    if (tid == 0) lastflag = (atomicAdd(cnt + dc, 1) == 4 * step + 3);
    __syncthreads();
    if (!lastflag) return;
    __threadfence();
    for (int idx = tid; idx < 512; idx += 256) {
        const int bb = idx & 31, dl = idx >> 5;
        const int d = dc * 16 + dl;
        float gg[4];
#pragma unroll
        for (int gate = 0; gate < 4; ++gate) {
            float s = bsum[gate * 1024 + d];
#pragma unroll
            for (int kcc = 0; kcc < 4; ++kcc)
                s += gp[((size_t)kcc * 4096 + gate * 1024 + d) * 32 + bb];
            gg[gate] = s;
        }
        const float cn = sigm(gg[1]) * c1[d * 32 + bb] + sigm(gg[0]) * tanhf(gg[2]);
        c1[d * 32 + bb] = cn;
        const unsigned short hb = f2bf(sigm(gg[3]) * tanhf(cn));
        z1out[bb * 2048 + d] = hb;
        z_all[((size_t)(step * 32 + bb)) * 2048 + d] = hb;
    }
}

// ----------------------------------------------------------- CE reduction
__global__ __launch_bounds__(256) void k_ce(const float* __restrict__ y, const float* __restrict__ bout,
                                            const int* __restrict__ ys_pad, float* __restrict__ out) {
    const int rrow = blockIdx.x;
    const int l = rrow >> 5, b = rrow & 31;
    const float* yp = y + (size_t)rrow * 5120;
    const int tid = threadIdx.x;
    __shared__ float red[256];
    float m = -1e30f;
    for (int c = tid; c < 5000; c += 256) m = fmaxf(m, yp[c] + bout[c]);
    red[tid] = m; __syncthreads();
    for (int s = 128; s; s >>= 1) { if (tid < s) red[tid] = fmaxf(red[tid], red[tid + s]); __syncthreads(); }
    const float gmax = red[0]; __syncthreads();
    float ss = 0.f;
    for (int c = tid; c < 5000; c += 256) ss += __expf(yp[c] + bout[c] - gmax);
    red[tid] = ss; __syncthreads();
    for (int s = 128; s; s >>= 1) { if (tid < s) red[tid] += red[tid + s]; __syncthreads(); }
    if (tid == 0) {
        const int tgt = (l < 100) ? ys_pad[b * 100 + l] : 4999;
        const float lt = yp[tgt] + bout[tgt];
        const float ce = logf(red[0]) + gmax - lt;
        atomicAdd(out, ce * (100.0f / 3232.0f));
    }
}

// ---------------------------------------------------------------------------
extern "C" void kernel_launch(void* const* d_in, const int* in_sizes, int n_in,
                              void* d_out, int out_size, void* d_ws, size_t ws_size,
                              hipStream_t stream) {
    const float* hs_pad = (const float*)d_in[0];
    const float* embed  = (const float*)d_in[1];
    const float* Wenc   = (const float*)d_in[2];
    const float* benc   = (const float*)d_in[3];
    const float* Wdec   = (const float*)d_in[4];
    const float* bdec   = (const float*)d_in[5];
    const float* W_ih0  = (const float*)d_in[6];
    const float* W_hh0  = (const float*)d_in[7];
    const float* b_ih0  = (const float*)d_in[8];
    const float* b_hh0  = (const float*)d_in[9];
    const float* W_ih1  = (const float*)d_in[10];
    const float* W_hh1  = (const float*)d_in[11];
    const float* b_ih1  = (const float*)d_in[12];
    const float* b_hh1  = (const float*)d_in[13];
    const float* Wout   = (const float*)d_in[14];
    const float* bout   = (const float*)d_in[15];
    const int*   hlens  = (const int*)d_in[16];
    const int*   ys_pad = (const int*)d_in[17];
    float* out = (float*)d_out;
    uint8_t* ws = (uint8_t*)d_ws;

    // workspace layout (bytes); Y (f32 [3328][5120], 68.2MB) aliases
    // [HS|PRE|start of WC0], all dead by the final GEMM.
    constexpr size_t OFF_HS   = 0;                       // 26,214,400
    constexpr size_t OFF_PRE  = OFF_HS   + 26214400;     // 26,214,400
    constexpr size_t OFF_WC0  = OFF_PRE  + 26214400;     // 25,165,824
    constexpr size_t OFF_WC1  = OFF_WC0  + 25165824;     // 16,777,216
    constexpr size_t OFF_WOUT = OFF_WC1  + 16777216;     // 20,971,520
    constexpr size_t OFF_WENC = OFF_WOUT + 20971520;     // 2,097,152
    constexpr size_t OFF_WDEC = OFF_WENC + 2097152;      // 2,097,152
    constexpr size_t OFF_EYS  = OFF_WDEC + 2097152;      // 6,619,136
    constexpr size_t OFF_ZALL = OFF_EYS  + 6619136;      // 13,631,488
    constexpr size_t OFF_GP   = OFF_ZALL + 13631488;     // 2,097,152
    constexpr size_t OFF_PART = OFF_GP   + 2097152;      // 1,048,576
    constexpr size_t OFF_LMAX = OFF_PART + 1048576;      // 1,024
    constexpr size_t OFF_LSUM = OFF_LMAX + 1024;         // 1,024
    constexpr size_t OFF_DQ   = OFF_LSUM + 1024;         // 65,536
    constexpr size_t OFF_X0R  = OFF_DQ   + 65536;        // 393,216  (2*32*3072*2)
    constexpr size_t OFF_X1R  = OFF_X0R  + 393216;       // 262,144  (2*32*2048*2)
    constexpr size_t OFF_C0   = OFF_X1R  + 262144;       // 131,072
    constexpr size_t OFF_C1   = OFF_C0   + 131072;       // 131,072
    constexpr size_t OFF_BS0  = OFF_C1   + 131072;       // 16,384
    constexpr size_t OFF_BS1  = OFF_BS0  + 16384;        // 16,384
    constexpr size_t OFF_CNT  = OFF_BS1  + 16384;        // 640
    constexpr size_t OFF_Y    = 0;

    unsigned short* HS   = (unsigned short*)(ws + OFF_HS);
    unsigned short* PRE  = (unsigned short*)(ws + OFF_PRE);
    unsigned short* WC0  = (unsigned short*)(ws + OFF_WC0);
    unsigned short* WC1  = (unsigned short*)(ws + OFF_WC1);
    unsigned short* WOUTP= (unsigned short*)(ws + OFF_WOUT);
    unsigned short* WENC = (unsigned short*)(ws + OFF_WENC);
    unsigned short* WDEC = (unsigned short*)(ws + OFF_WDEC);
    unsigned short* EYS  = (unsigned short*)(ws + OFF_EYS);
    unsigned short* ZALL = (unsigned short*)(ws + OFF_ZALL);
    float* GP    = (float*)(ws + OFF_GP);
    float* PART  = (float*)(ws + OFF_PART);
    float* LMAX  = (float*)(ws + OFF_LMAX);
    float* LSUM  = (float*)(ws + OFF_LSUM);
    unsigned short* DQ  = (unsigned short*)(ws + OFF_DQ);
    unsigned short* X0R = (unsigned short*)(ws + OFF_X0R);
    unsigned short* X1R = (unsigned short*)(ws + OFF_X1R);
    float* C0   = (float*)(ws + OFF_C0);
    float* C1   = (float*)(ws + OFF_C1);
    float* BS0  = (float*)(ws + OFF_BS0);
    float* BS1  = (float*)(ws + OFF_BS1);
    int* CNT_ATT = (int*)(ws + OFF_CNT);
    int* CNT0    = CNT_ATT + 32;
    int* CNT1    = CNT_ATT + 96;
    float* Y = (float*)(ws + OFF_Y);

    auto Zr = [&](void* p, int n_u32) {
        k_zero<<<dim3((n_u32 + 255) / 256), dim3(256), 0, stream>>>((unsigned int*)p, n_u32);
    };

    // ---- setup (re-done every call: ws/out are re-poisoned by the harness)
    Zr(X0R, 98304);                 // X0R[0]+X0R[1] (z0old slot of step 0 must be 0)
    Zr(X1R, 65536);                 // X1R[0]+X1R[1] (z0 init for k_dq, z1old step 0)
    Zr(C0, 32768);  Zr(C1, 32768);
    Zr(CNT_ATT, 160);
    Zr(d_out, 1);
    Zr(ZALL + (size_t)3232 * 2048, 98304);  // pad rows of z_all

    k_conv4<<<dim3(12800), dim3(256), 0, stream>>>(hs_pad, HS, 3276800);
    k_conv4<<<dim3(1024),  dim3(256), 0, stream>>>(Wenc, WENC, 262144);
    k_conv4<<<dim3(1024),  dim3(256), 0, stream>>>(Wdec, WDEC, 262144);
    k_cat2<<<dim3(49152), dim3(256), 0, stream>>>(W_ih0, W_hh0, WC0, 4096, 2048, 1024);
    k_cat2<<<dim3(32768), dim3(256), 0, stream>>>(W_ih1, W_hh1, WC1, 4096, 1024, 1024);
    k_woutpad<<<dim3(40960), dim3(256), 0, stream>>>(Wout, WOUTP);
    k_bsum<<<dim3(32), dim3(256), 0, stream>>>(b_ih0, b_hh0, b_ih1, b_hh1, BS0, BS1);
    k_eys<<<dim3(12928), dim3(256), 0, stream>>>(embed, ys_pad, EYS);

    // pre_enc = tanh(hs @ Wenc^T + benc), [12800][1024] bf16
    k_gemm128<<<dim3(8, 100), dim3(256), 0, stream>>>(HS, WENC, 1024, 1024, benc, PRE, (float*)nullptr, 0);
    // initial dq from z0 = 0 (X1R[0] cols 0..1023 are zeroed)
    k_dq<<<dim3(64), dim3(256), 0, stream>>>(WDEC, X1R, 2048, bdec, DQ);

    // ---- the scan: 101 steps, 3 kernels each
    for (int l = 0; l < 101; ++l) {
        unsigned short* X0l = X0R + (size_t)(l & 1) * 32 * 3072;
        unsigned short* X0n = X0R + (size_t)((l + 1) & 1) * 32 * 3072;
        unsigned short* X1l = X1R + (size_t)(l & 1) * 32 * 2048;
        unsigned short* X1n = X1R + (size_t)((l + 1) & 1) * 32 * 2048;
        k_att<<<dim3(256), dim3(256), 0, stream>>>(PRE, HS, DQ, hlens, EYS + (size_t)l * 32 * 1024,
                                                   X0l, PART, LMAX, LSUM, ZALL, CNT_ATT, l);
        k_cell0<<<dim3(256), dim3(256), 0, stream>>>(WC0, X0l, X1l, X0n + 2048, C0, GP, BS0, CNT0, l);
        k_cell1dq<<<dim3(320), dim3(256), 0, stream>>>(WC1, X1l, X1n + 1024, C1, GP, BS1, CNT1,
                                                       WDEC, bdec, DQ, ZALL, l);
    }

    // ---- output projection + CE
    k_gemm128<<<dim3(40, 26), dim3(256), 0, stream>>>(ZALL, WOUTP, 2048, 5120, (const float*)nullptr,
                                                      (unsigned short*)nullptr, Y, 1);
    k_ce<<<dim3(3232), dim3(256), 0, stream>>>(Y, bout, ys_pad, out);
}